// Round 2
// baseline (1118.466 us; speedup 1.0000x reference)
//
#include <hip/hip_runtime.h>
#include <hip/hip_bf16.h>

// DynamicLoRALinear: out = x @ W^T + b + 2.0 * ((x @ A[slot]) @ Bm[slot])
// fp32 I/O (reference dtype); compute in bf16 MFMA (threshold = 2% of max).
// d_in: 0=x[8192,4096] f32, 1=mapping[8] i32, 2=W[4096,4096] f32, 3=b[4096] f32,
//       4=lora_As[32,4096,16] f32, 5=lora_Bs[32,16,4096] f32. out: f32 [8192,4096].

typedef __bf16 bf16_t;
typedef __bf16 bf16x8 __attribute__((ext_vector_type(8)));
typedef __bf16 bf16x4 __attribute__((ext_vector_type(4)));
typedef float f32x4 __attribute__((ext_vector_type(4)));

#define M_DIM 8192
#define K_DIM 4096
#define N_DIM 4096
#define SCALE_F 2.0f

__device__ __forceinline__ void gload_lds16(const bf16_t* g, bf16_t* l) {
    __builtin_amdgcn_global_load_lds(
        (const __attribute__((address_space(1))) void*)g,
        (__attribute__((address_space(3))) void*)l, 16, 0, 0);
}

// ---------------- fp32 -> bf16 bulk convert (grid-stride, float4) ----------------
__global__ __launch_bounds__(256) void cvt_kernel(const float* __restrict__ src,
                                                  bf16_t* __restrict__ dst, int n4) {
    int i = blockIdx.x * 256 + threadIdx.x;
    const int stride = gridDim.x * 256;
    for (; i < n4; i += stride) {
        f32x4 v = ((const f32x4*)src)[i];
        bf16x4 o = {(bf16_t)v[0], (bf16_t)v[1], (bf16_t)v[2], (bf16_t)v[3]};
        ((bf16x4*)dst)[i] = o;
    }
}

// ------------- kernel 1: h_ws[m][r] = 2.0 * sum_i x[m,i] * A[slot][i][r] (fp32) ----
__global__ __launch_bounds__(256) void lora_h_kernel(
    const float* __restrict__ X,
    const float* __restrict__ lora_As,
    const int* __restrict__ mapping,
    float* __restrict__ h_ws)
{
    const int lane = threadIdx.x & 63;
    const int wave = threadIdx.x >> 6;
    const int m = blockIdx.x * 4 + wave;           // one wave per row
    const int slot = mapping[m >> 10];             // 1024 tokens per example
    const float* __restrict__ xrow = X + (size_t)m * K_DIM;
    const float* __restrict__ A = lora_As + (size_t)slot * K_DIM * 16;

    float h[16];
#pragma unroll
    for (int r = 0; r < 16; ++r) h[r] = 0.f;

    for (int i0 = lane * 4; i0 < K_DIM; i0 += 64 * 4) {
        f32x4 xv = *(const f32x4*)(xrow + i0);     // coalesced 16B/lane
#pragma unroll
        for (int j = 0; j < 4; ++j) {
            const float xf = xv[j];
            const f32x4* arow = (const f32x4*)(A + (size_t)(i0 + j) * 16);
            f32x4 a0 = arow[0], a1 = arow[1], a2 = arow[2], a3 = arow[3];
#pragma unroll
            for (int r = 0; r < 4; ++r) {
                h[r]      += xf * a0[r];
                h[r + 4]  += xf * a1[r];
                h[r + 8]  += xf * a2[r];
                h[r + 12] += xf * a3[r];
            }
        }
    }
#pragma unroll
    for (int r = 0; r < 16; ++r) {
        float v = h[r];
#pragma unroll
        for (int off = 32; off > 0; off >>= 1) v += __shfl_xor(v, off, 64);
        h[r] = v * SCALE_F;   // fold LoRA scaling here
    }
    if (lane == 0) {
        f32x4* dst = (f32x4*)(h_ws + (size_t)m * 16);
        dst[0] = (f32x4){h[0], h[1], h[2], h[3]};
        dst[1] = (f32x4){h[4], h[5], h[6], h[7]};
        dst[2] = (f32x4){h[8], h[9], h[10], h[11]};
        dst[3] = (f32x4){h[12], h[13], h[14], h[15]};
    }
}

// ---------------- kernel 2: main GEMM + bias + fused LoRA epilogue ----------------
// 128x128 tile, BK=32, 4 waves x (4x4) 16x16x32 bf16 MFMA.
// LDS layout [k8][row][8]: conflict-free ds_read_b128 fragments; in DIRECT mode
// also the contiguous wave-uniform-base + lane*16 mapping global_load_lds needs.
template <bool DIRECT>
__global__ __launch_bounds__(256) void gemm_lora_kernel(
    const bf16_t* __restrict__ Xb,       // [M,K] bf16 (DIRECT)
    const bf16_t* __restrict__ Wb,       // [N,K] bf16 (DIRECT)
    const float* __restrict__ Xf,        // [M,K] f32 (!DIRECT)
    const float* __restrict__ Wf,        // [N,K] f32 (!DIRECT)
    const float* __restrict__ bias,      // [N]
    const float* __restrict__ lora_Bs,   // [32,16,N] f32
    const int* __restrict__ mapping,     // [8]
    const float* __restrict__ h_ws,      // [M,16] f32 (already *2.0)
    float* __restrict__ out)             // [M,N] f32
{
    __shared__ bf16_t As[128 * 32];
    __shared__ bf16_t Bs[128 * 32];

    const int tid  = threadIdx.x;
    const int wave = tid >> 6;
    const int lane = tid & 63;
    const int bm0 = blockIdx.y * 128;
    const int bn0 = blockIdx.x * 128;
    const int wm0 = (wave >> 1) * 64;    // wave 2x2 -> 64x64 each
    const int wn0 = (wave & 1) * 64;
    const int r16 = lane & 15;
    const int kq  = lane >> 4;           // 0..3

    f32x4 acc[4][4];
#pragma unroll
    for (int i = 0; i < 4; ++i)
#pragma unroll
        for (int j = 0; j < 4; ++j) acc[i][j] = (f32x4){0.f, 0.f, 0.f, 0.f};

    for (int k0 = 0; k0 < K_DIM; k0 += 32) {
        if constexpr (DIRECT) {
            // chunk idx = k8*128+row; each wave: 2 chunksets of 64 x 16B per tile
#pragma unroll
            for (int p = 0; p < 2; ++p) {
                const int idx0 = (p * 4 + wave) * 64;  // wave-uniform LDS base
                const int idx  = idx0 + lane;
                const int k8   = idx >> 7;
                const int row  = idx & 127;
                gload_lds16(Xb + (size_t)(bm0 + row) * K_DIM + (k0 + k8 * 8),
                            As + (size_t)idx0 * 8);
                gload_lds16(Wb + (size_t)(bn0 + row) * K_DIM + (k0 + k8 * 8),
                            Bs + (size_t)idx0 * 8);
            }
        } else {
            // fp32 dwordx4 loads + in-register cvt + ds_write_b64
#pragma unroll
            for (int p = 0; p < 4; ++p) {
                const int v = tid + 256 * p;       // 0..1023
                const int row = v >> 3;
                const int k4  = v & 7;             // float4 index within the 32-K tile
                f32x4 xv = *(const f32x4*)(Xf + (size_t)(bm0 + row) * K_DIM + k0 + k4 * 4);
                f32x4 wv = *(const f32x4*)(Wf + (size_t)(bn0 + row) * K_DIM + k0 + k4 * 4);
                bf16x4 xa = {(bf16_t)xv[0], (bf16_t)xv[1], (bf16_t)xv[2], (bf16_t)xv[3]};
                bf16x4 wa = {(bf16_t)wv[0], (bf16_t)wv[1], (bf16_t)wv[2], (bf16_t)wv[3]};
                const size_t loff = ((size_t)(k4 >> 1) * 128 + row) * 8 + (k4 & 1) * 4;
                *(bf16x4*)(As + loff) = xa;
                *(bf16x4*)(Bs + loff) = wa;
            }
        }
        __syncthreads();

        bf16x8 af[4], bfr[4];
#pragma unroll
        for (int i = 0; i < 4; ++i) {
            af[i]  = *(const bf16x8*)(As + ((size_t)kq * 128 + wm0 + i * 16 + r16) * 8);
            bfr[i] = *(const bf16x8*)(Bs + ((size_t)kq * 128 + wn0 + i * 16 + r16) * 8);
        }
#pragma unroll
        for (int i = 0; i < 4; ++i)
#pragma unroll
            for (int j = 0; j < 4; ++j)
                acc[i][j] = __builtin_amdgcn_mfma_f32_16x16x32_bf16(af[i], bfr[j], acc[i][j], 0, 0, 0);
        __syncthreads();
    }

    // ---- fused LoRA: one extra MFMA K-tile (16 real K + 16 zero K) ----
    const int slot = mapping[bm0 >> 10];
    const bool hasK = (kq < 2);
    const int kq2 = hasK ? kq : 0;

    bf16x8 hfrag[4], bmf[4];
#pragma unroll
    for (int i = 0; i < 4; ++i) {
        const float* hp = h_ws + (size_t)(bm0 + wm0 + i * 16 + r16) * 16 + kq2 * 8;
        f32x4 h0 = *(const f32x4*)hp;
        f32x4 h1 = *(const f32x4*)(hp + 4);
#pragma unroll
        for (int jj = 0; jj < 4; ++jj) {
            hfrag[i][jj]     = hasK ? (bf16_t)h0[jj] : (bf16_t)0.f;
            hfrag[i][jj + 4] = hasK ? (bf16_t)h1[jj] : (bf16_t)0.f;
        }
    }
#pragma unroll
    for (int j = 0; j < 4; ++j) {
        const int o = bn0 + wn0 + j * 16 + r16;
#pragma unroll
        for (int jj = 0; jj < 8; ++jj) {
            const int r = kq2 * 8 + jj;
            const float v = lora_Bs[((size_t)slot * 16 + r) * N_DIM + o];
            bmf[j][jj] = hasK ? (bf16_t)v : (bf16_t)0.f;
        }
    }
#pragma unroll
    for (int i = 0; i < 4; ++i)
#pragma unroll
        for (int j = 0; j < 4; ++j)
            acc[i][j] = __builtin_amdgcn_mfma_f32_16x16x32_bf16(hfrag[i], bmf[j], acc[i][j], 0, 0, 0);

    // ---- bias + store (C/D: col=lane&15, row=(lane>>4)*4+e) ----
#pragma unroll
    for (int j = 0; j < 4; ++j) {
        const int o = bn0 + wn0 + j * 16 + r16;
        const float bv = bias[o];
#pragma unroll
        for (int i = 0; i < 4; ++i) {
#pragma unroll
            for (int e = 0; e < 4; ++e) {
                const int m = bm0 + wm0 + i * 16 + kq * 4 + e;
                out[(size_t)m * N_DIM + o] = acc[i][j][e] + bv;
            }
        }
    }
}

extern "C" void kernel_launch(void* const* d_in, const int* in_sizes, int n_in,
                              void* d_out, int out_size, void* d_ws, size_t ws_size,
                              hipStream_t stream) {
    const float* x        = (const float*)d_in[0];
    const int*   mapping  = (const int*)d_in[1];
    const float* W        = (const float*)d_in[2];
    const float* b        = (const float*)d_in[3];
    const float* lora_As  = (const float*)d_in[4];
    const float* lora_Bs  = (const float*)d_in[5];
    float* out = (float*)d_out;

    const size_t xb_bytes = (size_t)M_DIM * K_DIM * 2;   // 64 MB
    const size_t wb_bytes = (size_t)N_DIM * K_DIM * 2;   // 32 MB
    const size_t h_bytes  = (size_t)M_DIM * 16 * 4;      // 512 KB
    const bool direct = ws_size >= xb_bytes + wb_bytes + h_bytes;

    bf16_t* Xb = (bf16_t*)d_ws;
    bf16_t* Wb = (bf16_t*)((char*)d_ws + xb_bytes);
    float*  h_ws = direct ? (float*)((char*)d_ws + xb_bytes + wb_bytes)
                          : (float*)d_ws;

    lora_h_kernel<<<dim3(M_DIM / 4), 256, 0, stream>>>(x, lora_As, mapping, h_ws);

    if (direct) {
        cvt_kernel<<<dim3(4096), 256, 0, stream>>>(x, Xb, M_DIM * K_DIM / 4);
        cvt_kernel<<<dim3(2048), 256, 0, stream>>>(W, Wb, N_DIM * K_DIM / 4);
        gemm_lora_kernel<true><<<dim3(N_DIM / 128, M_DIM / 128), 256, 0, stream>>>(
            Xb, Wb, nullptr, nullptr, b, lora_Bs, mapping, h_ws, out);
    } else {
        gemm_lora_kernel<false><<<dim3(N_DIM / 128, M_DIM / 128), 256, 0, stream>>>(
            nullptr, nullptr, x, W, b, lora_Bs, mapping, h_ws, out);
    }
}

// Round 3
// 893.501 us; speedup vs baseline: 1.2518x; 1.2518x over previous
//
#include <hip/hip_runtime.h>
#include <hip/hip_bf16.h>

// DynamicLoRALinear: out = x @ W^T + b + 2.0 * ((x @ A[slot]) @ Bm[slot])
// fp32 I/O; compute in bf16 MFMA (passed R2: absmax 0.031 vs threshold 0.1425).
// d_in: 0=x[8192,4096] f32, 1=mapping[8] i32, 2=W[4096,4096] f32, 3=b[4096] f32,
//       4=lora_As[32,4096,16] f32, 5=lora_Bs[32,16,4096] f32. out: f32 [8192,4096].

typedef __bf16 bf16_t;
typedef __bf16 bf16x8 __attribute__((ext_vector_type(8)));
typedef __bf16 bf16x4 __attribute__((ext_vector_type(4)));
typedef float f32x4 __attribute__((ext_vector_type(4)));

#define M_DIM 8192
#define K_DIM 4096
#define N_DIM 4096
#define SCALE_F 2.0f

__device__ __forceinline__ void gload_lds16(const void* g, void* l) {
    __builtin_amdgcn_global_load_lds(
        (const __attribute__((address_space(1))) void*)g,
        (__attribute__((address_space(3))) void*)l, 16, 0, 0);
}

// ---------------- fp32 -> bf16 bulk convert (for W) ----------------
__global__ __launch_bounds__(256) void cvt_kernel(const float* __restrict__ src,
                                                  bf16_t* __restrict__ dst, int n4) {
    int i = blockIdx.x * 256 + threadIdx.x;
    const int stride = gridDim.x * 256;
    for (; i < n4; i += stride) {
        f32x4 v = ((const f32x4*)src)[i];
        bf16x4 o = {(bf16_t)v[0], (bf16_t)v[1], (bf16_t)v[2], (bf16_t)v[3]};
        ((bf16x4*)dst)[i] = o;
    }
}

// ------- kernel 1: h_ws[m][r] = 2.0 * sum_i x[m,i]*A[slot][i][r]; optionally emit Xb ----
// LDS-staged, fully coalesced. Block = 256 thr, 16 rows, K-tiles of 256.
// Lane decomposition: lane's f32x4 of A covers k = k0+s*16+(lane>>2), r = (lane&3)*4+c.
__global__ __launch_bounds__(256) void lora_h_kernel(
    const float* __restrict__ X,
    const float* __restrict__ lora_As,
    const int* __restrict__ mapping,
    float* __restrict__ h_ws,
    bf16_t* __restrict__ Xb)            // may be null (safe path)
{
    __shared__ float AT[256 * 16];      // [k_local][r]   16 KB
    __shared__ float XT[16 * 256];      // [row][k_local] 16 KB
    const int tid  = threadIdx.x;
    const int wave = tid >> 6;
    const int lane = tid & 63;
    const int m0   = blockIdx.x * 16;
    const int slot = mapping[m0 >> 10];          // 1024 rows per example, 16|1024
    const float* __restrict__ A = lora_As + (size_t)slot * K_DIM * 16;

    float h[4][4];
#pragma unroll
    for (int i = 0; i < 4; ++i)
#pragma unroll
        for (int c = 0; c < 4; ++c) h[i][c] = 0.f;

    for (int k0 = 0; k0 < K_DIM; k0 += 256) {
        // stage A tile: contiguous 4096 floats
#pragma unroll
        for (int c = 0; c < 4; ++c) {
            const int u = tid + 256 * c;
            f32x4 v = *(const f32x4*)(A + (size_t)k0 * 16 + u * 4);
            *(f32x4*)(AT + u * 4) = v;
        }
        // stage X tile (coalesced per row) + optional bf16 emission
#pragma unroll
        for (int c = 0; c < 4; ++c) {
            const int u = tid + 256 * c;
            const int row = u >> 6, ch = u & 63;
            const size_t goff = (size_t)(m0 + row) * K_DIM + k0 + ch * 4;
            f32x4 v = *(const f32x4*)(X + goff);
            *(f32x4*)(XT + row * 256 + ch * 4) = v;
            if (Xb) {
                bf16x4 o = {(bf16_t)v[0], (bf16_t)v[1], (bf16_t)v[2], (bf16_t)v[3]};
                *(bf16x4*)(Xb + goff) = o;
            }
        }
        __syncthreads();
        // compute: wave handles rows wave*4 .. wave*4+3
#pragma unroll 4
        for (int s = 0; s < 16; ++s) {
            f32x4 av = *(const f32x4*)(AT + s * 256 + lane * 4);   // conflict-free b128
#pragma unroll
            for (int i = 0; i < 4; ++i) {
                const float xv = XT[(wave * 4 + i) * 256 + s * 16 + (lane >> 2)]; // bcast
#pragma unroll
                for (int c = 0; c < 4; ++c) h[i][c] += xv * av[c];
            }
        }
        __syncthreads();
    }
    // reduce across lane bits 2..5 (lanes sharing lane&3 hold the same r-group)
#pragma unroll
    for (int i = 0; i < 4; ++i)
#pragma unroll
        for (int c = 0; c < 4; ++c) {
            float v = h[i][c];
            v += __shfl_xor(v, 4, 64);
            v += __shfl_xor(v, 8, 64);
            v += __shfl_xor(v, 16, 64);
            v += __shfl_xor(v, 32, 64);
            h[i][c] = v * SCALE_F;
        }
    if (lane < 4) {
#pragma unroll
        for (int i = 0; i < 4; ++i) {
            f32x4 o = {h[i][0], h[i][1], h[i][2], h[i][3]};
            *(f32x4*)(h_ws + (size_t)(m0 + wave * 4 + i) * 16 + lane * 4) = o;
        }
    }
}

// ---------------- shared GEMM body ----------------
// 128x128 tile, BK=32, 4 waves x (4x4) 16x16x32 bf16 MFMA, fused LoRA+bias epilogue.
// Supertile swizzle: n-low 3 bits -> XCD; W-panel L2-resident per XCD per epoch.
template <bool F32STAGE>
__device__ __forceinline__ void gemm_body(
    const void* __restrict__ Xp, const void* __restrict__ Wp,
    const float* __restrict__ bias, const float* __restrict__ lora_Bs,
    const int* __restrict__ mapping, const float* __restrict__ h_ws,
    float* __restrict__ out)
{
    __shared__ bf16_t smem[2 * 128 * 32 * (F32STAGE ? 2 : 1)];
    bf16_t* As = smem;
    bf16_t* Bs = smem + 128 * 32 * (F32STAGE ? 2 : 1);

    const int tid  = threadIdx.x;
    const int wave = tid >> 6;
    const int lane = tid & 63;
    const int bid  = blockIdx.x;
    const int n_t  = (bid & 7) + ((bid >> 9) << 3);  // 0..31
    const int m_t  = (bid >> 3) & 63;                // 0..63
    const int bm0 = m_t * 128;
    const int bn0 = n_t * 128;
    const int wm0 = (wave >> 1) * 64;
    const int wn0 = (wave & 1) * 64;
    const int r16 = lane & 15;
    const int kq  = lane >> 4;

    f32x4 acc[4][4];
#pragma unroll
    for (int i = 0; i < 4; ++i)
#pragma unroll
        for (int j = 0; j < 4; ++j) acc[i][j] = (f32x4){0.f, 0.f, 0.f, 0.f};

    for (int k0 = 0; k0 < K_DIM; k0 += 32) {
        if constexpr (!F32STAGE) {
            const bf16_t* Xb = (const bf16_t*)Xp;
            const bf16_t* Wb = (const bf16_t*)Wp;
            // bf16 chunks of 8: chunk idx = k8*128+row, 512 chunks/tile, 16B DMA
#pragma unroll
            for (int p = 0; p < 2; ++p) {
                const int idx0 = (p * 4 + wave) * 64;   // wave-uniform LDS base
                const int idx  = idx0 + lane;
                const int k8   = idx >> 7;
                const int row  = idx & 127;
                gload_lds16(Xb + (size_t)(bm0 + row) * K_DIM + (k0 + k8 * 8),
                            As + (size_t)idx0 * 8);
                gload_lds16(Wb + (size_t)(bn0 + row) * K_DIM + (k0 + k8 * 8),
                            Bs + (size_t)idx0 * 8);
            }
        } else {
            const float* Xf = (const float*)Xp;
            const float* Wf = (const float*)Wp;
            float* Asf = (float*)As;
            float* Bsf = (float*)Bs;
            // fp32 chunks of 4: chunk idx = k4*128+row, 1024 chunks/tile, 16B DMA
#pragma unroll
            for (int p = 0; p < 4; ++p) {
                const int idx0 = (p * 4 + wave) * 64;
                const int idx  = idx0 + lane;
                const int k4   = idx >> 7;
                const int row  = idx & 127;
                gload_lds16(Xf + (size_t)(bm0 + row) * K_DIM + (k0 + k4 * 4),
                            Asf + (size_t)idx0 * 4);
                gload_lds16(Wf + (size_t)(bn0 + row) * K_DIM + (k0 + k4 * 4),
                            Bsf + (size_t)idx0 * 4);
            }
        }
        __syncthreads();

        bf16x8 af[4], bfr[4];
        if constexpr (!F32STAGE) {
#pragma unroll
            for (int i = 0; i < 4; ++i) {
                af[i]  = *(const bf16x8*)(As + ((size_t)kq * 128 + wm0 + i * 16 + r16) * 8);
                bfr[i] = *(const bf16x8*)(Bs + ((size_t)kq * 128 + wn0 + i * 16 + r16) * 8);
            }
        } else {
            const float* Asf = (const float*)As;
            const float* Bsf = (const float*)Bs;
#pragma unroll
            for (int i = 0; i < 4; ++i) {
                const int ra = wm0 + i * 16 + r16;
                const int rb = wn0 + i * 16 + r16;
                f32x4 a0 = *(const f32x4*)(Asf + ((size_t)(kq * 2) * 128 + ra) * 4);
                f32x4 a1 = *(const f32x4*)(Asf + ((size_t)(kq * 2 + 1) * 128 + ra) * 4);
                f32x4 b0 = *(const f32x4*)(Bsf + ((size_t)(kq * 2) * 128 + rb) * 4);
                f32x4 b1 = *(const f32x4*)(Bsf + ((size_t)(kq * 2 + 1) * 128 + rb) * 4);
                af[i]  = (bf16x8){(bf16_t)a0[0], (bf16_t)a0[1], (bf16_t)a0[2], (bf16_t)a0[3],
                                  (bf16_t)a1[0], (bf16_t)a1[1], (bf16_t)a1[2], (bf16_t)a1[3]};
                bfr[i] = (bf16x8){(bf16_t)b0[0], (bf16_t)b0[1], (bf16_t)b0[2], (bf16_t)b0[3],
                                  (bf16_t)b1[0], (bf16_t)b1[1], (bf16_t)b1[2], (bf16_t)b1[3]};
            }
        }
#pragma unroll
        for (int i = 0; i < 4; ++i)
#pragma unroll
            for (int j = 0; j < 4; ++j)
                acc[i][j] = __builtin_amdgcn_mfma_f32_16x16x32_bf16(af[i], bfr[j], acc[i][j], 0, 0, 0);
        __syncthreads();
    }

    // ---- fused LoRA: one extra MFMA K-tile (16 real K + 16 zero K) ----
    const int slot = mapping[bm0 >> 10];
    const bool hasK = (kq < 2);
    const int kq2 = hasK ? kq : 0;

    bf16x8 hfrag[4], bmf[4];
#pragma unroll
    for (int i = 0; i < 4; ++i) {
        const float* hp = h_ws + (size_t)(bm0 + wm0 + i * 16 + r16) * 16 + kq2 * 8;
        f32x4 h0 = *(const f32x4*)hp;
        f32x4 h1 = *(const f32x4*)(hp + 4);
#pragma unroll
        for (int jj = 0; jj < 4; ++jj) {
            hfrag[i][jj]     = hasK ? (bf16_t)h0[jj] : (bf16_t)0.f;
            hfrag[i][jj + 4] = hasK ? (bf16_t)h1[jj] : (bf16_t)0.f;
        }
    }
#pragma unroll
    for (int j = 0; j < 4; ++j) {
        const int o = bn0 + wn0 + j * 16 + r16;
#pragma unroll
        for (int jj = 0; jj < 8; ++jj) {
            const int r = kq2 * 8 + jj;
            const float v = lora_Bs[((size_t)slot * 16 + r) * N_DIM + o];
            bmf[j][jj] = hasK ? (bf16_t)v : (bf16_t)0.f;
        }
    }
#pragma unroll
    for (int i = 0; i < 4; ++i)
#pragma unroll
        for (int j = 0; j < 4; ++j)
            acc[i][j] = __builtin_amdgcn_mfma_f32_16x16x32_bf16(hfrag[i], bmf[j], acc[i][j], 0, 0, 0);

    // ---- bias + store (C/D: col=lane&15, row=(lane>>4)*4+e) ----
#pragma unroll
    for (int j = 0; j < 4; ++j) {
        const int o = bn0 + wn0 + j * 16 + r16;
        const float bv = bias[o];
#pragma unroll
        for (int i = 0; i < 4; ++i) {
#pragma unroll
            for (int e = 0; e < 4; ++e) {
                const int m = bm0 + wm0 + i * 16 + kq * 4 + e;
                out[(size_t)m * N_DIM + o] = acc[i][j][e] + bv;
            }
        }
    }
}

__global__ __launch_bounds__(256) void gemm_lora_direct(
    const bf16_t* __restrict__ Xb, const bf16_t* __restrict__ Wb,
    const float* __restrict__ bias, const float* __restrict__ lora_Bs,
    const int* __restrict__ mapping, const float* __restrict__ h_ws,
    float* __restrict__ out)
{
    gemm_body<false>(Xb, Wb, bias, lora_Bs, mapping, h_ws, out);
}

__global__ __launch_bounds__(256) void gemm_lora_f32s(
    const float* __restrict__ Xf, const float* __restrict__ Wf,
    const float* __restrict__ bias, const float* __restrict__ lora_Bs,
    const int* __restrict__ mapping, const float* __restrict__ h_ws,
    float* __restrict__ out)
{
    gemm_body<true>(Xf, Wf, bias, lora_Bs, mapping, h_ws, out);
}

extern "C" void kernel_launch(void* const* d_in, const int* in_sizes, int n_in,
                              void* d_out, int out_size, void* d_ws, size_t ws_size,
                              hipStream_t stream) {
    const float* x        = (const float*)d_in[0];
    const int*   mapping  = (const int*)d_in[1];
    const float* W        = (const float*)d_in[2];
    const float* b        = (const float*)d_in[3];
    const float* lora_As  = (const float*)d_in[4];
    const float* lora_Bs  = (const float*)d_in[5];
    float* out = (float*)d_out;

    const size_t xb_bytes = (size_t)M_DIM * K_DIM * 2;   // 64 MB
    const size_t wb_bytes = (size_t)N_DIM * K_DIM * 2;   // 32 MB
    const size_t h_bytes  = (size_t)M_DIM * 16 * 4;      // 512 KB
    const bool direct = ws_size >= xb_bytes + wb_bytes + h_bytes;

    bf16_t* Xb = (bf16_t*)d_ws;
    bf16_t* Wb = (bf16_t*)((char*)d_ws + xb_bytes);
    float*  h_ws = direct ? (float*)((char*)d_ws + xb_bytes + wb_bytes)
                          : (float*)d_ws;

    lora_h_kernel<<<dim3(M_DIM / 16), 256, 0, stream>>>(
        x, lora_As, mapping, h_ws, direct ? Xb : nullptr);

    if (direct) {
        cvt_kernel<<<dim3(2048), 256, 0, stream>>>(W, Wb, N_DIM * K_DIM / 4);
        gemm_lora_direct<<<dim3(2048), 256, 0, stream>>>(
            Xb, Wb, b, lora_Bs, mapping, h_ws, out);
    } else {
        gemm_lora_f32s<<<dim3(2048), 256, 0, stream>>>(
            x, W, b, lora_Bs, mapping, h_ws, out);
    }
}

// Round 4
// 644.020 us; speedup vs baseline: 1.7367x; 1.3874x over previous
//
#include <hip/hip_runtime.h>
#include <hip/hip_bf16.h>

// DynamicLoRALinear: out = x @ W^T + b + 2.0 * ((x @ A[slot]) @ Bm[slot])
// fp32 I/O; compute in bf16 MFMA (absmax 0.031 vs threshold 0.1425).
// R4: BK=64 XOR-swizzled staging — coalesced global_load_lds (8 full lines/inst)
//     AND conflict-free ds_read_b128 (2-way max) simultaneously.

typedef __bf16 bf16_t;
typedef __bf16 bf16x8 __attribute__((ext_vector_type(8)));
typedef __bf16 bf16x4 __attribute__((ext_vector_type(4)));
typedef float f32x4 __attribute__((ext_vector_type(4)));

#define M_DIM 8192
#define K_DIM 4096
#define N_DIM 4096
#define SCALE_F 2.0f

__device__ __forceinline__ void gload_lds16(const void* g, void* l) {
    __builtin_amdgcn_global_load_lds(
        (const __attribute__((address_space(1))) void*)g,
        (__attribute__((address_space(3))) void*)l, 16, 0, 0);
}

// ---------------- fp32 -> bf16 bulk convert (for W) ----------------
__global__ __launch_bounds__(256) void cvt_kernel(const float* __restrict__ src,
                                                  bf16_t* __restrict__ dst, int n4) {
    int i = blockIdx.x * 256 + threadIdx.x;
    const int stride = gridDim.x * 256;
    for (; i < n4; i += stride) {
        f32x4 v = ((const f32x4*)src)[i];
        bf16x4 o = {(bf16_t)v[0], (bf16_t)v[1], (bf16_t)v[2], (bf16_t)v[3]};
        ((bf16x4*)dst)[i] = o;
    }
}

// ------- kernel 1: h_ws[m][r] = 2.0 * sum_i x[m,i]*A[slot][i][r]; also emits Xb ----
__global__ __launch_bounds__(256) void lora_h_kernel(
    const float* __restrict__ X,
    const float* __restrict__ lora_As,
    const int* __restrict__ mapping,
    float* __restrict__ h_ws,
    bf16_t* __restrict__ Xb)            // may be null (safe path)
{
    __shared__ float AT[256 * 16];      // [k_local][r]   16 KB
    __shared__ float XT[16 * 256];      // [row][k_local] 16 KB
    const int tid  = threadIdx.x;
    const int wave = tid >> 6;
    const int lane = tid & 63;
    const int m0   = blockIdx.x * 16;
    const int slot = mapping[m0 >> 10];
    const float* __restrict__ A = lora_As + (size_t)slot * K_DIM * 16;

    float h[4][4];
#pragma unroll
    for (int i = 0; i < 4; ++i)
#pragma unroll
        for (int c = 0; c < 4; ++c) h[i][c] = 0.f;

    for (int k0 = 0; k0 < K_DIM; k0 += 256) {
#pragma unroll
        for (int c = 0; c < 4; ++c) {
            const int u = tid + 256 * c;
            f32x4 v = *(const f32x4*)(A + (size_t)k0 * 16 + u * 4);
            *(f32x4*)(AT + u * 4) = v;
        }
#pragma unroll
        for (int c = 0; c < 4; ++c) {
            const int u = tid + 256 * c;
            const int row = u >> 6, ch = u & 63;
            const size_t goff = (size_t)(m0 + row) * K_DIM + k0 + ch * 4;
            f32x4 v = *(const f32x4*)(X + goff);
            *(f32x4*)(XT + row * 256 + ch * 4) = v;
            if (Xb) {
                bf16x4 o = {(bf16_t)v[0], (bf16_t)v[1], (bf16_t)v[2], (bf16_t)v[3]};
                *(bf16x4*)(Xb + goff) = o;
            }
        }
        __syncthreads();
#pragma unroll 4
        for (int s = 0; s < 16; ++s) {
            f32x4 av = *(const f32x4*)(AT + s * 256 + lane * 4);
#pragma unroll
            for (int i = 0; i < 4; ++i) {
                const float xv = XT[(wave * 4 + i) * 256 + s * 16 + (lane >> 2)];
#pragma unroll
                for (int c = 0; c < 4; ++c) h[i][c] += xv * av[c];
            }
        }
        __syncthreads();
    }
#pragma unroll
    for (int i = 0; i < 4; ++i)
#pragma unroll
        for (int c = 0; c < 4; ++c) {
            float v = h[i][c];
            v += __shfl_xor(v, 4, 64);
            v += __shfl_xor(v, 8, 64);
            v += __shfl_xor(v, 16, 64);
            v += __shfl_xor(v, 32, 64);
            h[i][c] = v * SCALE_F;
        }
    if (lane < 4) {
#pragma unroll
        for (int i = 0; i < 4; ++i) {
            f32x4 o = {h[i][0], h[i][1], h[i][2], h[i][3]};
            *(f32x4*)(h_ws + (size_t)(m0 + wave * 4 + i) * 16 + lane * 4) = o;
        }
    }
}

// ---- shared epilogue: fused LoRA MFMA K-tile + bias + store ----
__device__ __forceinline__ void epilogue(
    f32x4 (&acc)[4][4], const float* __restrict__ bias,
    const float* __restrict__ lora_Bs, const int* __restrict__ mapping,
    const float* __restrict__ h_ws, float* __restrict__ out,
    int bm0, int bn0, int wm0, int wn0, int r16, int kq)
{
    const int slot = mapping[bm0 >> 10];
    const bool hasK = (kq < 2);
    const int kq2 = hasK ? kq : 0;

    bf16x8 hfrag[4], bmf[4];
#pragma unroll
    for (int i = 0; i < 4; ++i) {
        const float* hp = h_ws + (size_t)(bm0 + wm0 + i * 16 + r16) * 16 + kq2 * 8;
        f32x4 h0 = *(const f32x4*)hp;
        f32x4 h1 = *(const f32x4*)(hp + 4);
#pragma unroll
        for (int jj = 0; jj < 4; ++jj) {
            hfrag[i][jj]     = hasK ? (bf16_t)h0[jj] : (bf16_t)0.f;
            hfrag[i][jj + 4] = hasK ? (bf16_t)h1[jj] : (bf16_t)0.f;
        }
    }
#pragma unroll
    for (int j = 0; j < 4; ++j) {
        const int o = bn0 + wn0 + j * 16 + r16;
#pragma unroll
        for (int jj = 0; jj < 8; ++jj) {
            const int r = kq2 * 8 + jj;
            const float v = lora_Bs[((size_t)slot * 16 + r) * N_DIM + o];
            bmf[j][jj] = hasK ? (bf16_t)v : (bf16_t)0.f;
        }
    }
#pragma unroll
    for (int i = 0; i < 4; ++i)
#pragma unroll
        for (int j = 0; j < 4; ++j)
            acc[i][j] = __builtin_amdgcn_mfma_f32_16x16x32_bf16(hfrag[i], bmf[j], acc[i][j], 0, 0, 0);

#pragma unroll
    for (int j = 0; j < 4; ++j) {
        const int o = bn0 + wn0 + j * 16 + r16;
        const float bv = bias[o];
#pragma unroll
        for (int i = 0; i < 4; ++i) {
#pragma unroll
            for (int e = 0; e < 4; ++e) {
                const int m = bm0 + wm0 + i * 16 + kq * 4 + e;
                out[(size_t)m * N_DIM + o] = acc[i][j][e] + bv;
            }
        }
    }
}

// ---------------- main GEMM (direct bf16, BK=64, XOR-swizzled LDS) ----------------
// Slot s (0..1023) per tile: row = s>>3, global k8 = (s&7)^(row&7).
// Staging: 8 consecutive lanes = one full 128-B line (coalesced).
// Fragment read row stride = 128 B = full bank wrap -> 2-way max (free).
__global__ __launch_bounds__(256) void gemm_lora_direct(
    const bf16_t* __restrict__ Xb, const bf16_t* __restrict__ Wb,
    const float* __restrict__ bias, const float* __restrict__ lora_Bs,
    const int* __restrict__ mapping, const float* __restrict__ h_ws,
    float* __restrict__ out)
{
    __shared__ bf16_t As[128 * 64];   // 16 KB
    __shared__ bf16_t Bs[128 * 64];   // 16 KB

    const int tid  = threadIdx.x;
    const int wave = tid >> 6;
    const int lane = tid & 63;
    const int bid  = blockIdx.x;
    const int n_t  = (bid & 7) + ((bid >> 9) << 3);  // 0..31 (XCD-aware)
    const int m_t  = (bid >> 3) & 63;                // 0..63
    const int bm0 = m_t * 128;
    const int bn0 = n_t * 128;
    const int wm0 = (wave >> 1) * 64;
    const int wn0 = (wave & 1) * 64;
    const int r16 = lane & 15;
    const int kq  = lane >> 4;

    f32x4 acc[4][4];
#pragma unroll
    for (int i = 0; i < 4; ++i)
#pragma unroll
        for (int j = 0; j < 4; ++j) acc[i][j] = (f32x4){0.f, 0.f, 0.f, 0.f};

    for (int k0 = 0; k0 < K_DIM; k0 += 64) {
#pragma unroll
        for (int p = 0; p < 4; ++p) {
            const int base = wave * 256 + p * 64;    // wave-uniform LDS slot base
            const int s    = base + lane;
            const int row  = s >> 3;
            const int k8g  = (s & 7) ^ (row & 7);
            gload_lds16(Xb + (size_t)(bm0 + row) * K_DIM + k0 + k8g * 8,
                        As + (size_t)base * 8);
            gload_lds16(Wb + (size_t)(bn0 + row) * K_DIM + k0 + k8g * 8,
                        Bs + (size_t)base * 8);
        }
        __syncthreads();

#pragma unroll
        for (int kh = 0; kh < 2; ++kh) {
            bf16x8 af[4], bfr[4];
            const int k8 = kh * 4 + kq;
#pragma unroll
            for (int i = 0; i < 4; ++i) {
                const int ra = wm0 + i * 16 + r16;
                const int rb = wn0 + i * 16 + r16;
                af[i]  = *(const bf16x8*)(As + ((size_t)ra * 8 + (k8 ^ (ra & 7))) * 8);
                bfr[i] = *(const bf16x8*)(Bs + ((size_t)rb * 8 + (k8 ^ (rb & 7))) * 8);
            }
#pragma unroll
            for (int i = 0; i < 4; ++i)
#pragma unroll
                for (int j = 0; j < 4; ++j)
                    acc[i][j] = __builtin_amdgcn_mfma_f32_16x16x32_bf16(af[i], bfr[j], acc[i][j], 0, 0, 0);
        }
        __syncthreads();
    }

    epilogue(acc, bias, lora_Bs, mapping, h_ws, out, bm0, bn0, wm0, wn0, r16, kq);
}

// ---------------- fallback: fp32 staging via global_load_lds, BK=32 ----------------
__global__ __launch_bounds__(256) void gemm_lora_f32s(
    const float* __restrict__ Xf, const float* __restrict__ Wf,
    const float* __restrict__ bias, const float* __restrict__ lora_Bs,
    const int* __restrict__ mapping, const float* __restrict__ h_ws,
    float* __restrict__ out)
{
    __shared__ float Asf[128 * 32];
    __shared__ float Bsf[128 * 32];

    const int tid  = threadIdx.x;
    const int wave = tid >> 6;
    const int lane = tid & 63;
    const int bid  = blockIdx.x;
    const int n_t  = (bid & 7) + ((bid >> 9) << 3);
    const int m_t  = (bid >> 3) & 63;
    const int bm0 = m_t * 128;
    const int bn0 = n_t * 128;
    const int wm0 = (wave >> 1) * 64;
    const int wn0 = (wave & 1) * 64;
    const int r16 = lane & 15;
    const int kq  = lane >> 4;

    f32x4 acc[4][4];
#pragma unroll
    for (int i = 0; i < 4; ++i)
#pragma unroll
        for (int j = 0; j < 4; ++j) acc[i][j] = (f32x4){0.f, 0.f, 0.f, 0.f};

    for (int k0 = 0; k0 < K_DIM; k0 += 32) {
#pragma unroll
        for (int p = 0; p < 4; ++p) {
            const int idx0 = (p * 4 + wave) * 64;
            const int idx  = idx0 + lane;
            const int k4   = idx >> 7;
            const int row  = idx & 127;
            gload_lds16(Xf + (size_t)(bm0 + row) * K_DIM + (k0 + k4 * 4),
                        Asf + (size_t)idx0 * 4);
            gload_lds16(Wf + (size_t)(bn0 + row) * K_DIM + (k0 + k4 * 4),
                        Bsf + (size_t)idx0 * 4);
        }
        __syncthreads();

        bf16x8 af[4], bfr[4];
#pragma unroll
        for (int i = 0; i < 4; ++i) {
            const int ra = wm0 + i * 16 + r16;
            const int rb = wn0 + i * 16 + r16;
            f32x4 a0 = *(const f32x4*)(Asf + ((size_t)(kq * 2) * 128 + ra) * 4);
            f32x4 a1 = *(const f32x4*)(Asf + ((size_t)(kq * 2 + 1) * 128 + ra) * 4);
            f32x4 b0 = *(const f32x4*)(Bsf + ((size_t)(kq * 2) * 128 + rb) * 4);
            f32x4 b1 = *(const f32x4*)(Bsf + ((size_t)(kq * 2 + 1) * 128 + rb) * 4);
            af[i]  = (bf16x8){(bf16_t)a0[0], (bf16_t)a0[1], (bf16_t)a0[2], (bf16_t)a0[3],
                              (bf16_t)a1[0], (bf16_t)a1[1], (bf16_t)a1[2], (bf16_t)a1[3]};
            bfr[i] = (bf16x8){(bf16_t)b0[0], (bf16_t)b0[1], (bf16_t)b0[2], (bf16_t)b0[3],
                              (bf16_t)b1[0], (bf16_t)b1[1], (bf16_t)b1[2], (bf16_t)b1[3]};
        }
#pragma unroll
        for (int i = 0; i < 4; ++i)
#pragma unroll
            for (int j = 0; j < 4; ++j)
                acc[i][j] = __builtin_amdgcn_mfma_f32_16x16x32_bf16(af[i], bfr[j], acc[i][j], 0, 0, 0);
        __syncthreads();
    }

    epilogue(acc, bias, lora_Bs, mapping, h_ws, out, bm0, bn0, wm0, wn0, r16, kq);
}

extern "C" void kernel_launch(void* const* d_in, const int* in_sizes, int n_in,
                              void* d_out, int out_size, void* d_ws, size_t ws_size,
                              hipStream_t stream) {
    const float* x        = (const float*)d_in[0];
    const int*   mapping  = (const int*)d_in[1];
    const float* W        = (const float*)d_in[2];
    const float* b        = (const float*)d_in[3];
    const float* lora_As  = (const float*)d_in[4];
    const float* lora_Bs  = (const float*)d_in[5];
    float* out = (float*)d_out;

    const size_t xb_bytes = (size_t)M_DIM * K_DIM * 2;   // 64 MB
    const size_t wb_bytes = (size_t)N_DIM * K_DIM * 2;   // 32 MB
    const size_t h_bytes  = (size_t)M_DIM * 16 * 4;      // 512 KB
    const bool direct = ws_size >= xb_bytes + wb_bytes + h_bytes;

    bf16_t* Xb = (bf16_t*)d_ws;
    bf16_t* Wb = (bf16_t*)((char*)d_ws + xb_bytes);
    float*  h_ws = direct ? (float*)((char*)d_ws + xb_bytes + wb_bytes)
                          : (float*)d_ws;

    lora_h_kernel<<<dim3(M_DIM / 16), 256, 0, stream>>>(
        x, lora_As, mapping, h_ws, direct ? Xb : nullptr);

    if (direct) {
        cvt_kernel<<<dim3(2048), 256, 0, stream>>>(W, Wb, N_DIM * K_DIM / 4);
        gemm_lora_direct<<<dim3(2048), 256, 0, stream>>>(
            Xb, Wb, b, lora_Bs, mapping, h_ws, out);
    } else {
        gemm_lora_f32s<<<dim3(2048), 256, 0, stream>>>(
            x, W, b, lora_Bs, mapping, h_ws, out);
    }
}

// Round 5
// 640.659 us; speedup vs baseline: 1.7458x; 1.0052x over previous
//
#include <hip/hip_runtime.h>
#include <hip/hip_bf16.h>

// DynamicLoRALinear: out = x @ W^T + b + 2.0 * ((x @ A[slot]) @ Bm[slot])
// fp32 I/O; compute in bf16 MFMA (absmax 0.031 vs threshold 0.1425).
// R5: replace VALU lora_h (~200us) with MFMA h-kernel fused with X->bf16 cvt.
//     Gemm unchanged from R4 (386us, XOR-swizzled BK=64 staging).

typedef __bf16 bf16_t;
typedef __bf16 bf16x8 __attribute__((ext_vector_type(8)));
typedef __bf16 bf16x4 __attribute__((ext_vector_type(4)));
typedef float f32x4 __attribute__((ext_vector_type(4)));

#define M_DIM 8192
#define K_DIM 4096
#define N_DIM 4096
#define SCALE_F 2.0f

__device__ __forceinline__ void gload_lds16(const void* g, void* l) {
    __builtin_amdgcn_global_load_lds(
        (const __attribute__((address_space(1))) void*)g,
        (__attribute__((address_space(3))) void*)l, 16, 0, 0);
}

// ---------------- fp32 -> bf16 bulk convert (for W) ----------------
__global__ __launch_bounds__(256) void cvt_kernel(const float* __restrict__ src,
                                                  bf16_t* __restrict__ dst, int n4) {
    int i = blockIdx.x * 256 + threadIdx.x;
    const int stride = gridDim.x * 256;
    for (; i < n4; i += stride) {
        f32x4 v = ((const f32x4*)src)[i];
        bf16x4 o = {(bf16_t)v[0], (bf16_t)v[1], (bf16_t)v[2], (bf16_t)v[3]};
        ((bf16x4*)dst)[i] = o;
    }
}

// ------- kernel 1: fused X->bf16 emit + h = 2.0*(x@A[slot]) via MFMA -------
// 256 blocks x 32 rows. K-tiles of 128. X staged via VGPR-cvt into the
// XOR-swizzled layout (slot = row*16 + (k8^(row&15)), 2-way banks max).
// A-tile transposed [r][k] pad 136 for B-fragments. wave = k-frag; LDS reduce.
__global__ __launch_bounds__(256) void lora_hx_kernel(
    const float* __restrict__ X,
    const float* __restrict__ lora_As,
    const int* __restrict__ mapping,
    float* __restrict__ h_ws,
    bf16_t* __restrict__ Xb)            // null in fallback path
{
    __shared__ bf16_t Xt[32 * 16 * 8];  // 8 KB, swizzled chunks of 8 bf16
    __shared__ bf16_t At[16 * 136];     // 4.25 KB, [r][k] padded (272B row, 16B-aligned)
    __shared__ float hred[4 * 2 * 16 * 16];  // 8 KB

    const int tid  = threadIdx.x;
    const int wave = tid >> 6;
    const int lane = tid & 63;
    const int bm0  = blockIdx.x * 32;
    const int slot = mapping[bm0 >> 10];
    const float* __restrict__ A = lora_As + (size_t)slot * (K_DIM * 16);

    const int srow = tid >> 3;          // 0..31 staging row
    const int sc2  = tid & 7;           // chunk-pair 0..7
    const int r16  = lane & 15;
    const int kq   = lane >> 4;

    f32x4 acc[2];
    acc[0] = (f32x4){0.f, 0.f, 0.f, 0.f};
    acc[1] = (f32x4){0.f, 0.f, 0.f, 0.f};

    for (int k0 = 0; k0 < K_DIM; k0 += 128) {
        // ---- stage X: 4 f32x4 -> 2 bf16x8 chunks (k8 = 2*sc2, 2*sc2+1) ----
        const float* xp = X + (size_t)(bm0 + srow) * K_DIM + k0 + sc2 * 16;
        f32x4 v0 = *(const f32x4*)(xp);
        f32x4 v1 = *(const f32x4*)(xp + 4);
        f32x4 v2 = *(const f32x4*)(xp + 8);
        f32x4 v3 = *(const f32x4*)(xp + 12);
        bf16x8 c0 = {(bf16_t)v0[0], (bf16_t)v0[1], (bf16_t)v0[2], (bf16_t)v0[3],
                     (bf16_t)v1[0], (bf16_t)v1[1], (bf16_t)v1[2], (bf16_t)v1[3]};
        bf16x8 c1 = {(bf16_t)v2[0], (bf16_t)v2[1], (bf16_t)v2[2], (bf16_t)v2[3],
                     (bf16_t)v3[0], (bf16_t)v3[1], (bf16_t)v3[2], (bf16_t)v3[3]};
        if (Xb) {
            bf16x8* xbp = (bf16x8*)(Xb + (size_t)(bm0 + srow) * K_DIM + k0 + sc2 * 16);
            xbp[0] = c0;
            xbp[1] = c1;
        }
        const int k8a = sc2 * 2, k8b = sc2 * 2 + 1;
        *(bf16x8*)(Xt + (srow * 16 + (k8a ^ (srow & 15))) * 8) = c0;
        *(bf16x8*)(Xt + (srow * 16 + (k8b ^ (srow & 15))) * 8) = c1;

        // ---- stage A-tile transposed: thread t -> k=t>>1, half=t&1 ----
        {
            const int kk = tid >> 1, half = tid & 1;
            const float* ap = A + (size_t)(k0 + kk) * 16 + half * 8;
            f32x4 a0 = *(const f32x4*)ap;
            f32x4 a1 = *(const f32x4*)(ap + 4);
#pragma unroll
            for (int rr = 0; rr < 4; ++rr) {
                At[(half * 8 + rr) * 136 + kk]     = (bf16_t)a0[rr];
                At[(half * 8 + 4 + rr) * 136 + kk] = (bf16_t)a1[rr];
            }
        }
        __syncthreads();

        // ---- MFMA: wave w = k-frag w; 2 m-frags of 16 rows ----
#pragma unroll
        for (int i = 0; i < 2; ++i) {
            const int row_l = i * 16 + r16;
            const int c = wave * 4 + kq;                       // chunk index
            bf16x8 af  = *(const bf16x8*)(Xt + (row_l * 16 + (c ^ (row_l & 15))) * 8);
            bf16x8 bfr = *(const bf16x8*)(At + r16 * 136 + wave * 32 + kq * 8);
            acc[i] = __builtin_amdgcn_mfma_f32_16x16x32_bf16(af, bfr, acc[i], 0, 0, 0);
        }
        __syncthreads();
    }

    // ---- cross-wave reduction (each wave holds k-frag partials) ----
#pragma unroll
    for (int i = 0; i < 2; ++i)
#pragma unroll
        for (int e = 0; e < 4; ++e)
            hred[wave * 512 + i * 256 + (kq * 4 + e) * 16 + r16] = acc[i][e];
    __syncthreads();
#pragma unroll
    for (int q = 0; q < 2; ++q) {
        const int entry = tid * 2 + q;          // 0..511
        const int row_l = entry >> 4, col = entry & 15;
        const int i = row_l >> 4, rr = row_l & 15;
        const int off = i * 256 + rr * 16 + col;
        float s = hred[off] + hred[512 + off] + hred[1024 + off] + hred[1536 + off];
        h_ws[(size_t)(bm0 + row_l) * 16 + col] = s * SCALE_F;
    }
}

// ---- shared epilogue: fused LoRA MFMA K-tile + bias + store ----
__device__ __forceinline__ void epilogue(
    f32x4 (&acc)[4][4], const float* __restrict__ bias,
    const float* __restrict__ lora_Bs, const int* __restrict__ mapping,
    const float* __restrict__ h_ws, float* __restrict__ out,
    int bm0, int bn0, int wm0, int wn0, int r16, int kq)
{
    const int slot = mapping[bm0 >> 10];
    const bool hasK = (kq < 2);
    const int kq2 = hasK ? kq : 0;

    bf16x8 hfrag[4], bmf[4];
#pragma unroll
    for (int i = 0; i < 4; ++i) {
        const float* hp = h_ws + (size_t)(bm0 + wm0 + i * 16 + r16) * 16 + kq2 * 8;
        f32x4 h0 = *(const f32x4*)hp;
        f32x4 h1 = *(const f32x4*)(hp + 4);
#pragma unroll
        for (int jj = 0; jj < 4; ++jj) {
            hfrag[i][jj]     = hasK ? (bf16_t)h0[jj] : (bf16_t)0.f;
            hfrag[i][jj + 4] = hasK ? (bf16_t)h1[jj] : (bf16_t)0.f;
        }
    }
#pragma unroll
    for (int j = 0; j < 4; ++j) {
        const int o = bn0 + wn0 + j * 16 + r16;
#pragma unroll
        for (int jj = 0; jj < 8; ++jj) {
            const int r = kq2 * 8 + jj;
            const float v = lora_Bs[((size_t)slot * 16 + r) * N_DIM + o];
            bmf[j][jj] = hasK ? (bf16_t)v : (bf16_t)0.f;
        }
    }
#pragma unroll
    for (int i = 0; i < 4; ++i)
#pragma unroll
        for (int j = 0; j < 4; ++j)
            acc[i][j] = __builtin_amdgcn_mfma_f32_16x16x32_bf16(hfrag[i], bmf[j], acc[i][j], 0, 0, 0);

#pragma unroll
    for (int j = 0; j < 4; ++j) {
        const int o = bn0 + wn0 + j * 16 + r16;
        const float bv = bias[o];
#pragma unroll
        for (int i = 0; i < 4; ++i) {
#pragma unroll
            for (int e = 0; e < 4; ++e) {
                const int m = bm0 + wm0 + i * 16 + kq * 4 + e;
                out[(size_t)m * N_DIM + o] = acc[i][j][e] + bv;
            }
        }
    }
}

// ---------------- main GEMM (direct bf16, BK=64, XOR-swizzled LDS) ----------------
__global__ __launch_bounds__(256) void gemm_lora_direct(
    const bf16_t* __restrict__ Xb, const bf16_t* __restrict__ Wb,
    const float* __restrict__ bias, const float* __restrict__ lora_Bs,
    const int* __restrict__ mapping, const float* __restrict__ h_ws,
    float* __restrict__ out)
{
    __shared__ bf16_t As[128 * 64];   // 16 KB
    __shared__ bf16_t Bs[128 * 64];   // 16 KB

    const int tid  = threadIdx.x;
    const int wave = tid >> 6;
    const int lane = tid & 63;
    const int bid  = blockIdx.x;
    const int n_t  = (bid & 7) + ((bid >> 9) << 3);  // 0..31 (XCD-aware)
    const int m_t  = (bid >> 3) & 63;                // 0..63
    const int bm0 = m_t * 128;
    const int bn0 = n_t * 128;
    const int wm0 = (wave >> 1) * 64;
    const int wn0 = (wave & 1) * 64;
    const int r16 = lane & 15;
    const int kq  = lane >> 4;

    f32x4 acc[4][4];
#pragma unroll
    for (int i = 0; i < 4; ++i)
#pragma unroll
        for (int j = 0; j < 4; ++j) acc[i][j] = (f32x4){0.f, 0.f, 0.f, 0.f};

    for (int k0 = 0; k0 < K_DIM; k0 += 64) {
#pragma unroll
        for (int p = 0; p < 4; ++p) {
            const int base = wave * 256 + p * 64;    // wave-uniform LDS slot base
            const int s    = base + lane;
            const int row  = s >> 3;
            const int k8g  = (s & 7) ^ (row & 7);
            gload_lds16(Xb + (size_t)(bm0 + row) * K_DIM + k0 + k8g * 8,
                        As + (size_t)base * 8);
            gload_lds16(Wb + (size_t)(bn0 + row) * K_DIM + k0 + k8g * 8,
                        Bs + (size_t)base * 8);
        }
        __syncthreads();

#pragma unroll
        for (int kh = 0; kh < 2; ++kh) {
            bf16x8 af[4], bfr[4];
            const int k8 = kh * 4 + kq;
#pragma unroll
            for (int i = 0; i < 4; ++i) {
                const int ra = wm0 + i * 16 + r16;
                const int rb = wn0 + i * 16 + r16;
                af[i]  = *(const bf16x8*)(As + ((size_t)ra * 8 + (k8 ^ (ra & 7))) * 8);
                bfr[i] = *(const bf16x8*)(Bs + ((size_t)rb * 8 + (k8 ^ (rb & 7))) * 8);
            }
#pragma unroll
            for (int i = 0; i < 4; ++i)
#pragma unroll
                for (int j = 0; j < 4; ++j)
                    acc[i][j] = __builtin_amdgcn_mfma_f32_16x16x32_bf16(af[i], bfr[j], acc[i][j], 0, 0, 0);
        }
        __syncthreads();
    }

    epilogue(acc, bias, lora_Bs, mapping, h_ws, out, bm0, bn0, wm0, wn0, r16, kq);
}

// ---------------- fallback: fp32 staging via global_load_lds, BK=32 ----------------
__global__ __launch_bounds__(256) void gemm_lora_f32s(
    const float* __restrict__ Xf, const float* __restrict__ Wf,
    const float* __restrict__ bias, const float* __restrict__ lora_Bs,
    const int* __restrict__ mapping, const float* __restrict__ h_ws,
    float* __restrict__ out)
{
    __shared__ float Asf[128 * 32];
    __shared__ float Bsf[128 * 32];

    const int tid  = threadIdx.x;
    const int wave = tid >> 6;
    const int lane = tid & 63;
    const int bid  = blockIdx.x;
    const int n_t  = (bid & 7) + ((bid >> 9) << 3);
    const int m_t  = (bid >> 3) & 63;
    const int bm0 = m_t * 128;
    const int bn0 = n_t * 128;
    const int wm0 = (wave >> 1) * 64;
    const int wn0 = (wave & 1) * 64;
    const int r16 = lane & 15;
    const int kq  = lane >> 4;

    f32x4 acc[4][4];
#pragma unroll
    for (int i = 0; i < 4; ++i)
#pragma unroll
        for (int j = 0; j < 4; ++j) acc[i][j] = (f32x4){0.f, 0.f, 0.f, 0.f};

    for (int k0 = 0; k0 < K_DIM; k0 += 32) {
#pragma unroll
        for (int p = 0; p < 4; ++p) {
            const int idx0 = (p * 4 + wave) * 64;
            const int idx  = idx0 + lane;
            const int k4   = idx >> 7;
            const int row  = idx & 127;
            gload_lds16(Xf + (size_t)(bm0 + row) * K_DIM + (k0 + k4 * 4),
                        Asf + (size_t)idx0 * 4);
            gload_lds16(Wf + (size_t)(bn0 + row) * K_DIM + (k0 + k4 * 4),
                        Bsf + (size_t)idx0 * 4);
        }
        __syncthreads();

        bf16x8 af[4], bfr[4];
#pragma unroll
        for (int i = 0; i < 4; ++i) {
            const int ra = wm0 + i * 16 + r16;
            const int rb = wn0 + i * 16 + r16;
            f32x4 a0 = *(const f32x4*)(Asf + ((size_t)(kq * 2) * 128 + ra) * 4);
            f32x4 a1 = *(const f32x4*)(Asf + ((size_t)(kq * 2 + 1) * 128 + ra) * 4);
            f32x4 b0 = *(const f32x4*)(Bsf + ((size_t)(kq * 2) * 128 + rb) * 4);
            f32x4 b1 = *(const f32x4*)(Bsf + ((size_t)(kq * 2 + 1) * 128 + rb) * 4);
            af[i]  = (bf16x8){(bf16_t)a0[0], (bf16_t)a0[1], (bf16_t)a0[2], (bf16_t)a0[3],
                              (bf16_t)a1[0], (bf16_t)a1[1], (bf16_t)a1[2], (bf16_t)a1[3]};
            bfr[i] = (bf16x8){(bf16_t)b0[0], (bf16_t)b0[1], (bf16_t)b0[2], (bf16_t)b0[3],
                              (bf16_t)b1[0], (bf16_t)b1[1], (bf16_t)b1[2], (bf16_t)b1[3]};
        }
#pragma unroll
        for (int i = 0; i < 4; ++i)
#pragma unroll
            for (int j = 0; j < 4; ++j)
                acc[i][j] = __builtin_amdgcn_mfma_f32_16x16x32_bf16(af[i], bfr[j], acc[i][j], 0, 0, 0);
        __syncthreads();
    }

    epilogue(acc, bias, lora_Bs, mapping, h_ws, out, bm0, bn0, wm0, wn0, r16, kq);
}

extern "C" void kernel_launch(void* const* d_in, const int* in_sizes, int n_in,
                              void* d_out, int out_size, void* d_ws, size_t ws_size,
                              hipStream_t stream) {
    const float* x        = (const float*)d_in[0];
    const int*   mapping  = (const int*)d_in[1];
    const float* W        = (const float*)d_in[2];
    const float* b        = (const float*)d_in[3];
    const float* lora_As  = (const float*)d_in[4];
    const float* lora_Bs  = (const float*)d_in[5];
    float* out = (float*)d_out;

    const size_t xb_bytes = (size_t)M_DIM * K_DIM * 2;   // 64 MB
    const size_t wb_bytes = (size_t)N_DIM * K_DIM * 2;   // 32 MB
    const size_t h_bytes  = (size_t)M_DIM * 16 * 4;      // 512 KB
    const bool direct = ws_size >= xb_bytes + wb_bytes + h_bytes;

    bf16_t* Xb = (bf16_t*)d_ws;
    bf16_t* Wb = (bf16_t*)((char*)d_ws + xb_bytes);
    float*  h_ws = direct ? (float*)((char*)d_ws + xb_bytes + wb_bytes)
                          : (float*)d_ws;

    lora_hx_kernel<<<dim3(M_DIM / 32), 256, 0, stream>>>(
        x, lora_As, mapping, h_ws, direct ? Xb : nullptr);

    if (direct) {
        cvt_kernel<<<dim3(2048), 256, 0, stream>>>(W, Wb, N_DIM * K_DIM / 4);
        gemm_lora_direct<<<dim3(2048), 256, 0, stream>>>(
            Xb, Wb, b, lora_Bs, mapping, h_ws, out);
    } else {
        gemm_lora_f32s<<<dim3(2048), 256, 0, stream>>>(
            x, W, b, lora_Bs, mapping, h_ws, out);
    }
}